// Round 1
// baseline (344.791 us; speedup 1.0000x reference)
//
#include <hip/hip_runtime.h>

#define BB 4
#define DD 4096
#define FF 128
#define SLOPE 0.2f

typedef float f32x4 __attribute__((ext_vector_type(4)));
typedef short bf16x8 __attribute__((ext_vector_type(8)));

__device__ __forceinline__ unsigned short f2bf(float v) {
  union { float f; unsigned u; } c; c.f = v;
  unsigned r = c.u + 0x7FFFu + ((c.u >> 16) & 1u);
  return (unsigned short)(r >> 16);
}
__device__ __forceinline__ float bf2f(unsigned short u) {
  union { unsigned u; float f; } c; c.u = ((unsigned)u) << 16;
  return c.f;
}

// Kernel A: Wh = x@W (f32 regs) -> WhT bf16 [B][F][D]; fs, ft (f32); mb[b] = max(0, max_j ft)
__global__ __launch_bounds__(256) void kA(
    const float* __restrict__ x, const float* __restrict__ W,
    const float* __restrict__ a_src, const float* __restrict__ a_tgt,
    unsigned short* __restrict__ WhT, float* __restrict__ fs,
    float* __restrict__ ft, int* __restrict__ mb)
{
  __shared__ __align__(16) float Ws[128 * 128];
  __shared__ __align__(16) float xs[64 * 128];     // reused as reduction scratch
  __shared__ unsigned short st[128 * 66];
  const int t = threadIdx.x;
  const int wg = blockIdx.x;            // 256 wgs x 64 rows
  const int row0 = wg * 64;             // flat row in [0, B*D)
  const int b = row0 / DD;
  const int i_in_b = row0 % DD;

  for (int i = t * 4; i < 128 * 128; i += 1024)
    *(float4*)&Ws[i] = *(const float4*)&W[i];
  for (int i = t * 4; i < 64 * 128; i += 1024)
    *(float4*)&xs[i] = *(const float4*)&x[(size_t)row0 * FF + i];
  __syncthreads();

  const int fg = t & 31, rg = t >> 5;
  const int f0 = fg * 4, r0 = rg * 8;
  float acc[8][4];
  #pragma unroll
  for (int a = 0; a < 8; ++a) acc[a][0] = acc[a][1] = acc[a][2] = acc[a][3] = 0.f;
  for (int k = 0; k < 128; ++k) {
    float4 wq = *(const float4*)&Ws[k * 128 + f0];
    #pragma unroll
    for (int rr = 0; rr < 8; ++rr) {
      float xv = xs[(r0 + rr) * 128 + k];
      acc[rr][0] += xv * wq.x; acc[rr][1] += xv * wq.y;
      acc[rr][2] += xv * wq.z; acc[rr][3] += xv * wq.w;
    }
  }
  __syncthreads();   // done reading xs; reuse as reduction scratch
  float* red_s = xs;             // [64][33]
  float* red_t = xs + 64 * 33;   // [64][33]
  float4 as4 = *(const float4*)&a_src[f0];
  float4 at4 = *(const float4*)&a_tgt[f0];
  #pragma unroll
  for (int rr = 0; rr < 8; ++rr) {
    float ps = acc[rr][0]*as4.x + acc[rr][1]*as4.y + acc[rr][2]*as4.z + acc[rr][3]*as4.w;
    float pt = acc[rr][0]*at4.x + acc[rr][1]*at4.y + acc[rr][2]*at4.z + acc[rr][3]*at4.w;
    red_s[(r0 + rr) * 33 + fg] = ps;
    red_t[(r0 + rr) * 33 + fg] = pt;
    st[(f0 + 0) * 66 + r0 + rr] = f2bf(acc[rr][0]);
    st[(f0 + 1) * 66 + r0 + rr] = f2bf(acc[rr][1]);
    st[(f0 + 2) * 66 + r0 + rr] = f2bf(acc[rr][2]);
    st[(f0 + 3) * 66 + r0 + rr] = f2bf(acc[rr][3]);
  }
  __syncthreads();
  if (t < 64) {
    float s = 0.f, tt = 0.f;
    #pragma unroll
    for (int q = 0; q < 32; ++q) { s += red_s[t * 33 + q]; tt += red_t[t * 33 + q]; }
    fs[row0 + t] = s;
    ft[row0 + t] = tt;
    float m = fmaxf(0.f, tt);
    #pragma unroll
    for (int s2 = 1; s2 < 64; s2 <<= 1) m = fmaxf(m, __shfl_xor(m, s2));
    if (t == 0) atomicMax(&mb[b], __float_as_int(m));  // m >= 0: int-order == float-order
  }
  // WhT bf16 writeout (coalesced per 64-wide row chunks)
  for (int p = 0; p < 32; ++p) {
    int idx = p * 256 + t;
    int f = idx >> 6, rl = idx & 63;
    WhT[((size_t)b * FF + f) * DD + i_in_b + rl] = st[f * 66 + rl];
  }
}

// Kernel C: fused scores + softmax + attn write + PV MFMA. 16 rows / wg, 8 waves.
__global__ __launch_bounds__(512) void kC(
    const int* __restrict__ adj, const float* __restrict__ fs,
    const float* __restrict__ ft, const int* __restrict__ mbp,
    const unsigned short* __restrict__ WhT, const float* __restrict__ bias,
    float* __restrict__ hout, float* __restrict__ attn)
{
  __shared__ __align__(16) unsigned short p_lds[16 * 4096];  // 128 KB, XOR-swizzled
  __shared__ float sums[16];
  __shared__ float invs[16];
  const int t = threadIdx.x;
  const int w = t >> 6, l = t & 63;
  const int bid = blockIdx.x;
  const int b = bid >> 8;
  const int i0 = (bid & 255) << 4;
  const float mbv = __int_as_float(mbp[b]);   // >= 0, upper bound of ft
  const int r0 = 2 * w, r1 = r0 + 1;
  const float fs0 = fs[b * DD + i0 + r0];
  const float fs1 = fs[b * DD + i0 + r1];
  const float M0 = fmaxf(0.f, fs0 + mbv);     // >= row max of e (lrelu monotone)
  const float M1 = fmaxf(0.f, fs1 + mbv);
  const float* ftb = ft + b * DD;
  const int* adj0 = adj + ((size_t)b * DD + i0 + r0) * DD;
  const int* adj1 = adj + ((size_t)b * DD + i0 + r1) * DD;
  const unsigned sw0 = (unsigned)(r0 & 7) << 4;
  const unsigned sw1 = (unsigned)(r1 & 7) << 4;
  float sum0 = 0.f, sum1 = 0.f;

  auto pf = [](float fsv, float ftv, int av, float Mv) {
    float e = fsv + ftv;
    e = e > 0.f ? e : SLOPE * e;   // leaky_relu
    e = av ? e : 0.f;              // masked scores become 0 (NOT -inf)
    return __expf(e - Mv);
  };

  // Phase 1: stream adj, compute p, stash bf16 p in LDS, accumulate row sums
  #pragma unroll 2
  for (int c = 0; c < DD; c += 256) {
    const int j = c + l * 4;
    float4 f4 = *(const float4*)(ftb + j);
    int4 a0 = *(const int4*)(adj0 + j);
    int4 a1 = *(const int4*)(adj1 + j);
    float p00 = pf(fs0, f4.x, a0.x, M0), p01 = pf(fs0, f4.y, a0.y, M0);
    float p02 = pf(fs0, f4.z, a0.z, M0), p03 = pf(fs0, f4.w, a0.w, M0);
    float p10 = pf(fs1, f4.x, a1.x, M1), p11 = pf(fs1, f4.y, a1.y, M1);
    float p12 = pf(fs1, f4.z, a1.z, M1), p13 = pf(fs1, f4.w, a1.w, M1);
    sum0 += (p00 + p01) + (p02 + p03);
    sum1 += (p10 + p11) + (p12 + p13);
    ushort4 q0; q0.x = f2bf(p00); q0.y = f2bf(p01); q0.z = f2bf(p02); q0.w = f2bf(p03);
    ushort4 q1; q1.x = f2bf(p10); q1.y = f2bf(p11); q1.z = f2bf(p12); q1.w = f2bf(p13);
    unsigned o0 = (((unsigned)r0 * 8192u) + (unsigned)j * 2u) ^ sw0;
    unsigned o1 = (((unsigned)r1 * 8192u) + (unsigned)j * 2u) ^ sw1;
    *(ushort4*)&p_lds[o0 >> 1] = q0;
    *(ushort4*)&p_lds[o1 >> 1] = q1;
  }
  #pragma unroll
  for (int s = 1; s < 64; s <<= 1) {
    sum0 += __shfl_xor(sum0, s);
    sum1 += __shfl_xor(sum1, s);
  }
  if (l == 0) { sums[r0] = sum0; sums[r1] = sum1; }
  __syncthreads();
  if (t < 16) invs[t] = 1.0f / sums[t];
  __syncthreads();

  // Phase 2a: write normalized attn (stores overlap the MFMA below)
  float* arow_base = attn + (size_t)b * DD * DD + (size_t)i0 * DD;
  #pragma unroll 2
  for (int r = 0; r < 16; ++r) {
    const float iv = invs[r];
    unsigned o = (((unsigned)r * 8192u) + (unsigned)t * 16u) ^ ((unsigned)(r & 7) << 4);
    ushort4 q0 = *(const ushort4*)&p_lds[o >> 1];
    ushort4 q1 = *(const ushort4*)&p_lds[(o >> 1) + 4];
    float4 v0, v1;
    v0.x = bf2f(q0.x) * iv; v0.y = bf2f(q0.y) * iv; v0.z = bf2f(q0.z) * iv; v0.w = bf2f(q0.w) * iv;
    v1.x = bf2f(q1.x) * iv; v1.y = bf2f(q1.y) * iv; v1.z = bf2f(q1.z) * iv; v1.w = bf2f(q1.w) * iv;
    float* dst = arow_base + (size_t)r * DD + t * 8;
    *(float4*)dst = v0;
    *(float4*)(dst + 4) = v1;
  }

  // Phase 2b: PV via mfma_f32_16x16x32_bf16. Wave w -> f-tile f0=16w, rows i0..i0+15.
  const int f0 = w * 16;
  const int c15 = l & 15;       // A row AND B/D column (f)
  const int kg = l >> 4;
  const unsigned abase = (unsigned)c15 * 8192u + (unsigned)kg * 16u;
  const unsigned asw = (unsigned)(c15 & 7) << 4;
  const unsigned short* wrow = WhT + ((size_t)b * FF + f0 + c15) * DD + kg * 8;
  f32x4 acc0 = {0.f, 0.f, 0.f, 0.f}, acc1 = {0.f, 0.f, 0.f, 0.f};
  for (int ks = 0; ks < 128; ks += 2) {
    unsigned ao0 = (abase + (unsigned)ks * 64u) ^ asw;
    unsigned ao1 = (abase + (unsigned)(ks + 1) * 64u) ^ asw;
    bf16x8 A0 = *(const bf16x8*)&p_lds[ao0 >> 1];
    bf16x8 A1 = *(const bf16x8*)&p_lds[ao1 >> 1];
    bf16x8 B0 = *(const bf16x8*)&wrow[(size_t)ks * 32];
    bf16x8 B1 = *(const bf16x8*)&wrow[(size_t)(ks + 1) * 32];
    acc0 = __builtin_amdgcn_mfma_f32_16x16x32_bf16(A0, B0, acc0, 0, 0, 0);
    acc1 = __builtin_amdgcn_mfma_f32_16x16x32_bf16(A1, B1, acc1, 0, 0, 0);
  }
  f32x4 acc = acc0 + acc1;
  const float bv = bias[f0 + c15];
  #pragma unroll
  for (int q = 0; q < 4; ++q) {
    int orow = kg * 4 + q;       // C/D: row = (lane>>4)*4 + reg
    float val = acc[q] * invs[orow] + bv;
    hout[((size_t)b * DD + i0 + orow) * FF + f0 + c15] = val;
  }
}

extern "C" void kernel_launch(void* const* d_in, const int* in_sizes, int n_in,
                              void* d_out, int out_size, void* d_ws, size_t ws_size,
                              hipStream_t stream) {
  const float* x     = (const float*)d_in[0];
  const int*   adj   = (const int*)d_in[1];
  const float* W     = (const float*)d_in[2];
  const float* a_src = (const float*)d_in[3];
  const float* a_tgt = (const float*)d_in[4];
  const float* bias  = (const float*)d_in[5];
  char* ws = (char*)d_ws;
  unsigned short* WhT = (unsigned short*)ws;            // 4 MB
  float* fs = (float*)(ws + 4194304);                   // 64 KB
  float* ft = (float*)(ws + 4259840);                   // 64 KB
  int*   mb = (int*)(ws + 4325376);                     // 16 B
  float* hout = (float*)d_out;                          // [B][D][F]
  float* attn = hout + (size_t)BB * DD * FF;            // [B][D][D]
  (void)hipMemsetAsync(mb, 0, BB * sizeof(int), stream);
  kA<<<256, 256, 0, stream>>>(x, W, a_src, a_tgt, WhT, fs, ft, mb);
  kC<<<1024, 512, 0, stream>>>(adj, fs, ft, mb, WhT, bias, hout, attn);
}